// Round 1
// baseline (524.568 us; speedup 1.0000x reference)
//
#include <hip/hip_runtime.h>
#include <stdint.h>

#define D   512
#define BM  128
#define BN  128
#define BK  64

typedef __attribute__((ext_vector_type(8))) short short8;   // 8 bf16 = 4 VGPRs
typedef __attribute__((ext_vector_type(4))) float f32x4;    // MFMA accumulator

__device__ __forceinline__ void gld_lds16(const void* g, void* l) {
  __builtin_amdgcn_global_load_lds(
      (const __attribute__((address_space(1))) void*)g,
      (__attribute__((address_space(3))) void*)l, 16, 0, 0);
}

__device__ __forceinline__ unsigned short f2bf(float f) {
  unsigned u = __float_as_uint(f);
  u += 0x7fffu + ((u >> 16) & 1u);           // round-to-nearest-even
  return (unsigned short)(u >> 16);
}

// One wave per row: load 512 fp32, shuffle-reduce sum of squares, store 512 bf16.
__global__ void norm_kernel(const float* __restrict__ img,
                            const float* __restrict__ prof,
                            unsigned short* __restrict__ outA,
                            unsigned short* __restrict__ outB, int n) {
  int wave = threadIdx.x >> 6, lane = threadIdx.x & 63;
  int gw = blockIdx.x * 4 + wave;
  if (gw >= 2 * n) return;
  const float* src;
  unsigned short* dst;
  if (gw < n) { src = img  + (size_t)gw * D;       dst = outA + (size_t)gw * D; }
  else        { src = prof + (size_t)(gw - n) * D; dst = outB + (size_t)(gw - n) * D; }

  const float4* s4 = (const float4*)src + lane * 2;
  float4 a = s4[0], b = s4[1];
  float ss = a.x*a.x + a.y*a.y + a.z*a.z + a.w*a.w
           + b.x*b.x + b.y*b.y + b.z*b.z + b.w*b.w;
#pragma unroll
  for (int m = 1; m < 64; m <<= 1) ss += __shfl_xor(ss, m, 64);
  float inv = 1.0f / fmaxf(sqrtf(ss), 1e-12f);

  unsigned short h0 = f2bf(a.x*inv), h1 = f2bf(a.y*inv), h2 = f2bf(a.z*inv), h3 = f2bf(a.w*inv);
  unsigned short h4 = f2bf(b.x*inv), h5 = f2bf(b.y*inv), h6 = f2bf(b.z*inv), h7 = f2bf(b.w*inv);
  uint4 pk;
  pk.x = (unsigned)h0 | ((unsigned)h1 << 16);
  pk.y = (unsigned)h2 | ((unsigned)h3 << 16);
  pk.z = (unsigned)h4 | ((unsigned)h5 << 16);
  pk.w = (unsigned)h6 | ((unsigned)h7 << 16);
  *(uint4*)(dst + lane * 8) = pk;
}

__device__ __forceinline__ float softplus_f(float x) {  // log(1+e^x)
  return fmaxf(x, 0.0f) + __logf(1.0f + __expf(-fabsf(x)));
}

// C = A(img) x B(prof)^T on bf16, fused SigLIP loss epilogue.
// LDS layout per tile: slot c (16B chunks) = row*8 + (kb ^ (row&7))  [xor swizzle]
__global__ __launch_bounds__(256) void siglip_gemm(
    const unsigned short* __restrict__ A, const unsigned short* __restrict__ B,
    const float* __restrict__ scale_p, const float* __restrict__ bias_p,
    const int* __restrict__ buckets_p, float* __restrict__ out, int n) {
  __shared__ __align__(16) unsigned short sA[BM * BK];
  __shared__ __align__(16) unsigned short sB[BN * BK];
  __shared__ float red[4];

  int tid = threadIdx.x;
  int lane = tid & 63, wave = tid >> 6;
  int quad = lane >> 4, l16 = lane & 15;

  // 16x16 superblock swizzle for L2 locality
  int nb = n >> 7;                      // blocks per dim (128)
  int sb = blockIdx.x >> 8;             // 256 blocks per superblock
  int r8 = blockIdx.x & 255;
  int sbm = sb % (nb >> 4), sbn = sb / (nb >> 4);
  int bm = sbm * 16 + (r8 & 15);
  int bn = sbn * 16 + (r8 >> 4);

  int rowB = bm * BM, colB = bn * BN;
  const unsigned short* Ag = A + (size_t)rowB * D;
  const unsigned short* Bg = B + (size_t)colB * D;

  // scalar params (latency hidden under GEMM)
  float scale = __expf(scale_p[0]);
  float bias  = bias_p[0];
  int buckets = buckets_p[0];

  int wm = (wave >> 1) * 64, wn = (wave & 1) * 64;

  f32x4 acc[4][4];
#pragma unroll
  for (int i = 0; i < 4; i++)
#pragma unroll
    for (int j = 0; j < 4; j++) { acc[i][j].x = 0.f; acc[i][j].y = 0.f; acc[i][j].z = 0.f; acc[i][j].w = 0.f; }

  for (int k0 = 0; k0 < D; k0 += BK) {
    // stage A then B: 1024 chunks each, 4 per thread per matrix
#pragma unroll
    for (int p = 0; p < 4; p++) {
      int c = p * 256 + tid;
      int r = c >> 3, j = c & 7;
      int kb = j ^ (r & 7);
      gld_lds16(Ag + (size_t)r * D + k0 + kb * 8, &sA[c * 8]);
    }
#pragma unroll
    for (int p = 0; p < 4; p++) {
      int c = p * 256 + tid;
      int r = c >> 3, j = c & 7;
      int kb = j ^ (r & 7);
      gld_lds16(Bg + (size_t)r * D + k0 + kb * 8, &sB[c * 8]);
    }
    __syncthreads();   // compiler emits vmcnt(0) drain before barrier

#pragma unroll
    for (int ks = 0; ks < 2; ks++) {
      int kb = ks * 4 + quad;
      short8 af[4], bf[4];
#pragma unroll
      for (int t = 0; t < 4; t++) {
        int ra = wm + t * 16 + l16;
        af[t] = *(const short8*)&sA[(ra * 8 + (kb ^ (ra & 7))) * 8];
        int rb = wn + t * 16 + l16;
        bf[t] = *(const short8*)&sB[(rb * 8 + (kb ^ (rb & 7))) * 8];
      }
#pragma unroll
      for (int tm = 0; tm < 4; tm++)
#pragma unroll
        for (int tn = 0; tn < 4; tn++)
          acc[tm][tn] = __builtin_amdgcn_mfma_f32_16x16x32_bf16(af[tm], bf[tn], acc[tm][tn], 0, 0, 0);
    }
    __syncthreads();
  }

  // ---- fused loss epilogue ----
  // C/D layout (m89/m91): col = lane&15, row = quad*4 + reg
  float local = 0.0f;
  if (buckets == 1) {
#pragma unroll
    for (int tm = 0; tm < 4; tm++)
#pragma unroll
      for (int tn = 0; tn < 4; tn++)
#pragma unroll
        for (int e = 0; e < 4; e++) {
          int r = rowB + wm + tm * 16 + quad * 4 + e;
          int c = colB + wn + tn * 16 + l16;
          float v = acc[tm][tn][e] * scale + bias;
          // z = diag ? v : -v ; contribution = softplus(-z)
          float x = (r == c) ? -v : v;
          local += softplus_f(x);
        }
  } else {
    unsigned bs = (unsigned)n / (unsigned)buckets;
#pragma unroll
    for (int tm = 0; tm < 4; tm++)
#pragma unroll
      for (int tn = 0; tn < 4; tn++)
#pragma unroll
        for (int e = 0; e < 4; e++) {
          int r = rowB + wm + tm * 16 + quad * 4 + e;
          int c = colB + wn + tn * 16 + l16;
          if ((unsigned)r / bs != (unsigned)c / bs) continue;
          float v = acc[tm][tn][e] * scale + bias;
          float x = (r == c) ? -v : v;
          local += softplus_f(x);
        }
  }

#pragma unroll
  for (int m = 1; m < 64; m <<= 1) local += __shfl_xor(local, m, 64);
  if (lane == 0) red[wave] = local;
  __syncthreads();
  if (tid == 0) {
    float bsum = red[0] + red[1] + red[2] + red[3];
    atomicAdd(out, bsum * (1.0f / (float)n));   // /bs then mean over buckets == /n
  }
}

extern "C" void kernel_launch(void* const* d_in, const int* in_sizes, int n_in,
                              void* d_out, int out_size, void* d_ws, size_t ws_size,
                              hipStream_t stream) {
  const float* img  = (const float*)d_in[0];
  const float* prof = (const float*)d_in[1];
  const float* lsc  = (const float*)d_in[2];
  const float* bia  = (const float*)d_in[3];
  const int*   bkt  = (const int*)d_in[4];
  float* out = (float*)d_out;

  int n = in_sizes[0] / D;                       // 16384
  unsigned short* wsA = (unsigned short*)d_ws;   // n*512 bf16
  unsigned short* wsB = wsA + (size_t)n * D;     // n*512 bf16

  hipMemsetAsync(out, 0, sizeof(float), stream);
  norm_kernel<<<(2 * n + 3) / 4, 256, 0, stream>>>(img, prof, wsA, wsB, n);
  int nb = n / BM;
  siglip_gemm<<<nb * nb, 256, 0, stream>>>(wsA, wsB, lsc, bia, bkt, out, n);
}